// Round 1
// 332.150 us; speedup vs baseline: 1.0913x; 1.0913x over previous
//
#include <hip/hip_runtime.h>

#define NB 8
#define CH 128
#define HH 160
#define WW 160
#define SPILL 100
#define LDS_ROWS 60   // rows [SPILL..159] in LDS: 60*128*4 = 30720 B -> 5 blocks/CU (exactly full grid resident)

// DPP full-wave shifts; bound_ctrl=1 zero-fills out-of-wave = channel zero-padding.
__device__ __forceinline__ float dpp_up1(float x) {   // lane i <- lane i-1, lane 0 <- 0
    return __int_as_float(__builtin_amdgcn_update_dpp(0, __float_as_int(x), 0x138, 0xF, 0xF, true));
}
__device__ __forceinline__ float dpp_dn1(float x) {   // lane i <- lane i+1, lane 63 <- 0
    return __int_as_float(__builtin_amdgcn_update_dpp(0, __float_as_int(x), 0x130, 0xF, 0xF, true));
}

// 9-tap conv along channels; thread t owns channels 2t,2t+1. 3x3-tap trees (chain: 3 fma + 2 add).
__device__ __forceinline__ float2 conv9(float2 p, const float* w, float b) {
    float m1x = dpp_up1(p.x), m1y = dpp_up1(p.y);
    float m2x = dpp_up1(m1x), m2y = dpp_up1(m1y);
    float p1x = dpp_dn1(p.x), p1y = dpp_dn1(p.y);
    float p2x = dpp_dn1(p1x), p2y = dpp_dn1(p1y);
    float e0=m2x,e1=m2y,e2=m1x,e3=m1y,e4=p.x,e5=p.y,e6=p1x,e7=p1y,e8=p2x,e9=p2y;
    float ax = fmaf(w[0], e0, b);       ax = fmaf(w[3], e3, ax); ax = fmaf(w[6], e6, ax);
    float bx = w[1]*e1;                 bx = fmaf(w[4], e4, bx); bx = fmaf(w[7], e7, bx);
    float cx = w[2]*e2;                 cx = fmaf(w[5], e5, cx); cx = fmaf(w[8], e8, cx);
    float ay = fmaf(w[0], e1, b);       ay = fmaf(w[3], e4, ay); ay = fmaf(w[6], e7, ay);
    float by = w[1]*e2;                 by = fmaf(w[4], e5, by); by = fmaf(w[7], e8, by);
    float cy = w[2]*e3;                 cy = fmaf(w[5], e6, cy); cy = fmaf(w[8], e9, cy);
    return make_float2((ax + bx) + cx, (ay + by) + cy);
}

// K0: NCHW -> NHWC. Tile: 32 c x 128 p. Reads float4 (512B/row), writes float2 (128B segs).
__global__ __launch_bounds__(256) void k0_transpose(const float* __restrict__ x,
                                                    float* __restrict__ A) {
    __shared__ float t[32][132];   // 132: float4-aligned row, breaks worst banking
    int p0 = blockIdx.x * 128;
    int c0 = blockIdx.y * 32;
    int n  = blockIdx.z;
    int tid = threadIdx.x;
    const float* xn = x + (size_t)n * CH * HH * WW;
    float* An = A + (size_t)n * HH * WW * CH;
    #pragma unroll
    for (int j = 0; j < 4; j++) {
        int c = j*8 + tid/32;
        int q4 = (tid%32)*4;
        float4 v = *(const float4*)(xn + (size_t)(c0 + c) * (HH*WW) + p0 + q4);
        *(float4*)&t[c][q4] = v;
    }
    __syncthreads();
    #pragma unroll
    for (int j = 0; j < 8; j++) {
        int p  = j*16 + tid/16;
        int cq = (tid%16)*2;
        float2 v = make_float2(t[cq][p], t[cq+1][p]);
        *(float2*)(An + (size_t)(p0 + p) * CH + c0 + cq) = v;
    }
}

// K1: fused down+up scan over H, in-place on A. 1 wave per (n,w) column; 5 blocks/CU.
// Up-pass re-read ring deepened to 16 (covers ~800 cyc of L2/L3/HBM latency).
__global__ __launch_bounds__(64) void k1_vert(float* __restrict__ A,
        const float* __restrict__ wdp, const float* __restrict__ bdp,
        const float* __restrict__ wup, const float* __restrict__ bup) {
    __shared__ float lds[LDS_ROWS][CH];   // relu(d) rows SPILL..159; x at [r][lane], y at [r][64+lane] (2-way = free)
    int lane = threadIdx.x;
    int w = blockIdx.x, n = blockIdx.y;
    float wd[9], wu[9];
    #pragma unroll
    for (int j = 0; j < 9; j++) { wd[j] = wdp[j]; wu[j] = wup[j]; }
    float bd = bdp[0], bu = bup[0];
    float* col = A + ((size_t)n * HH * WW + w) * CH + 2*lane;
    const size_t RS = (size_t)WW * CH;

    // ---- down: d[h] = relu(conv(d[h-1]))+x[h]; rows <SPILL spill relu(d) in-place, rest to LDS ----
    float2 d;
    float2 qf[16];
    #pragma unroll
    for (int i = 0; i < 16; i++) qf[i] = *(const float2*)(col + (size_t)i * RS);
    for (int hb = 0; hb < HH; hb += 16) {
        #pragma unroll
        for (int k = 0; k < 16; k++) {
            int h = hb + k;
            float2 xr = qf[k];
            if (h + 16 < HH) qf[k] = *(const float2*)(col + (size_t)(h+16) * RS);
            if (h == 0) d = xr;
            else {
                float2 cv = conv9(d, wd, bd);
                d.x = fmaxf(cv.x, 0.f) + xr.x;
                d.y = fmaxf(cv.y, 0.f) + xr.y;
            }
            float rx = fmaxf(d.x, 0.f), ry = fmaxf(d.y, 0.f);
            if (h < SPILL) *(float2*)(col + (size_t)h * RS) = make_float2(rx, ry);
            else { lds[h-SPILL][lane] = rx; lds[h-SPILL][64+lane] = ry; }
        }
    }

    // ---- up: u[s] = relu(conv(u[s-1]))+relu(d[159-s]); 16-deep mixed LDS/global ring ----
    float2 u;
    float2 tf[16];
    #pragma unroll
    for (int k = 0; k < 16; k++) {
        int h = HH - 1 - k;   // 159..144, all >= SPILL
        tf[k] = make_float2(lds[h-SPILL][lane], lds[h-SPILL][64+lane]);
    }
    for (int sb = 0; sb < HH; sb += 16) {
        #pragma unroll
        for (int k = 0; k < 16; k++) {
            int s = sb + k;
            int h = HH - 1 - s;
            float2 t2 = tf[k];
            int h2 = h - 16;
            if (h2 >= SPILL)    tf[k] = make_float2(lds[h2-SPILL][lane], lds[h2-SPILL][64+lane]);
            else if (h2 >= 0)   tf[k] = *(const float2*)(col + (size_t)h2 * RS);
            if (s == 0) u = t2;
            else {
                float2 cv = conv9(u, wu, bu);
                u.x = fmaxf(cv.x, 0.f) + t2.x;
                u.y = fmaxf(cv.y, 0.f) + t2.y;
            }
            *(float2*)(col + (size_t)h * RS) = u;
        }
    }
}

// K2: fused left+right scan over W + FUSED flip-transpose output (k3 eliminated).
// 1 wave per (n,h) row; 5 blocks/CU; LDS unchanged at 30720 B.
// Right-scan step s (w = 159-s) produces the final value for out[n][c][159-h][s].
// Output tile (32 w' x 128 c) is staged in the spill LDS rows that the ring
// prefetch consumed >=16 iterations earlier: tile row for step s = (179-s) % 60.
// XOR swizzle col^(row&31): spill writes/ring reads stay a lane permutation
// (conflict-free); transposed flush reads spread across banks (<=2-way).
__global__ __launch_bounds__(64) void k2_horz(float* __restrict__ A,
        const float* __restrict__ wlp, const float* __restrict__ blp,
        const float* __restrict__ wrp, const float* __restrict__ brp,
        float* __restrict__ out) {
    __shared__ float lds[LDS_ROWS][CH];
    int lane = threadIdx.x;
    int hp = blockIdx.x, n = blockIdx.y;
    float wl[9], wr[9];
    #pragma unroll
    for (int j = 0; j < 9; j++) { wl[j] = wlp[j]; wr[j] = wrp[j]; }
    float bl = blp[0], br = brp[0];
    float* row0 = A + ((size_t)n * HH + hp) * WW * CH + 2*lane;
    const size_t PS = CH;

    // ---- left scan: spill relu(l); rows >=SPILL to swizzled LDS ----
    float2 l;
    float2 qf[16];
    #pragma unroll
    for (int i = 0; i < 16; i++) qf[i] = *(const float2*)(row0 + (size_t)i * PS);
    for (int ab = 0; ab < WW; ab += 16) {
        #pragma unroll
        for (int k = 0; k < 16; k++) {
            int a = ab + k;
            float2 xr = qf[k];
            if (a + 16 < WW) qf[k] = *(const float2*)(row0 + (size_t)(a+16) * PS);
            xr.x = fmaxf(xr.x, 0.f); xr.y = fmaxf(xr.y, 0.f);
            if (a == 0) l = xr;
            else {
                float2 cv = conv9(l, wl, bl);
                l.x = fmaxf(cv.x, 0.f) + xr.x;
                l.y = fmaxf(cv.y, 0.f) + xr.y;
            }
            float rx = fmaxf(l.x, 0.f), ry = fmaxf(l.y, 0.f);
            if (a < SPILL) *(float2*)(row0 + (size_t)a * PS) = make_float2(rx, ry);
            else {
                int r = a - SPILL;
                int sw = r & 31;
                lds[r][lane ^ sw] = rx;
                lds[r][64 + (lane ^ sw)] = ry;
            }
        }
    }

    // ---- right scan with fused flipped-transposed output ----
    float2 u;
    float2 tf[16];
    #pragma unroll
    for (int k = 0; k < 16; k++) {
        int a = WW - 1 - k;              // 159..144, all >= SPILL
        int r = a - SPILL;
        int sw = r & 31;
        tf[k] = make_float2(lds[r][lane ^ sw], lds[r][64 + (lane ^ sw)]);
    }
    int ho  = HH - 1 - hp;
    int l31 = lane & 31;
    int hi  = lane >> 5;
    // flush base: lane handles channel c = 2*i + hi, position w' = sb + l31
    float* ob = out + ((size_t)(n * CH + hi) * HH + ho) * WW + l31;
    int jf = (179 - l31) % 60;    // tile row holding w' = l31 of the current block
    int js = 59;                  // tile row for current step s (decrements, wraps 0->59)

    for (int sb = 0; sb < WW; sb += 32) {
        #pragma unroll
        for (int kk = 0; kk < 32; kk++) {
            int s = sb + kk;
            int a = WW - 1 - s;
            float2 t6 = tf[kk & 15];
            int a2 = a - 16;
            if (a2 >= SPILL) {
                int r = a2 - SPILL;
                int sw = r & 31;
                tf[kk & 15] = make_float2(lds[r][lane ^ sw], lds[r][64 + (lane ^ sw)]);
            } else if (a2 >= 0) {
                tf[kk & 15] = *(const float2*)(row0 + (size_t)a2 * PS);
            }
            if (s == 0) u = t6;
            else {
                float2 cv = conv9(u, wr, br);
                u.x = fmaxf(cv.x, 0.f) + t6.x;
                u.y = fmaxf(cv.y, 0.f) + t6.y;
            }
            // stage final relu'd value into the just-consumed tile row
            {
                int sw = js & 31;
                lds[js][lane ^ sw]        = fmaxf(u.x, 0.f);
                lds[js][64 + (lane ^ sw)] = fmaxf(u.y, 0.f);
            }
            js = js ? js - 1 : 59;
        }
        // flush w' = sb..sb+31 for all 128 channels; 128B line-aligned segments
        {
            int jx = jf & 31;
            int pl = jf * 128 + (hi << 6);
            const float* lp = &lds[0][0];
            #pragma unroll
            for (int i = 0; i < 64; i++) {
                float v = lp[pl + (i ^ jx)];
                ob[(size_t)(2*i) * (HH*WW) + sb] = v;
            }
            jf -= 32; if (jf < 0) jf += 60;
        }
    }
}

extern "C" void kernel_launch(void* const* d_in, const int* in_sizes, int n_in,
                              void* d_out, int out_size, void* d_ws, size_t ws_size,
                              hipStream_t stream) {
    (void)in_sizes; (void)n_in; (void)out_size; (void)ws_size;
    const float* x  = (const float*)d_in[0];
    const float* wd = (const float*)d_in[1];
    const float* bd = (const float*)d_in[2];
    const float* wu = (const float*)d_in[3];
    const float* bu = (const float*)d_in[4];
    const float* wl = (const float*)d_in[5];
    const float* bl = (const float*)d_in[6];
    const float* wr = (const float*)d_in[7];
    const float* br = (const float*)d_in[8];
    float* out = (float*)d_out;
    float* A   = (float*)d_ws;   // needs N*H*W*C*4 = 104,857,600 bytes

    dim3 g0(HH*WW/128, CH/32, NB), b0(256);
    k0_transpose<<<g0, b0, 0, stream>>>(x, A);

    dim3 g1(WW, NB), b1(64);
    k1_vert<<<g1, b1, 0, stream>>>(A, wd, bd, wu, bu);

    dim3 g2(HH, NB);
    k2_horz<<<g2, b1, 0, stream>>>(A, wl, bl, wr, br, out);
}